// Round 4
// baseline (9790.389 us; speedup 1.0000x reference)
//
#include <hip/hip_runtime.h>
#include <cstdint>
#include <cstddef>

// Problem constants (from reference setup_inputs; steps=30 is a fixed scalar
// input — graph capture requires a fixed launch sequence, so hardcoded).
#define B_DIM  1024
#define DIN    512
#define H_DIM  1024
#define DOUT   512
#define NB     10
#define STEPS  30

typedef _Float16 half_t;
typedef __attribute__((ext_vector_type(8))) _Float16 frag_ab;  // 8 fp16 in 4 VGPRs
typedef __attribute__((ext_vector_type(4))) float    frag_cd;  // 4 fp32 acc

// async global->LDS, 16B per lane; LDS dest is wave-uniform base + lane*16
__device__ __forceinline__ void gload16(const void* g, void* l) {
    __builtin_amdgcn_global_load_lds(
        (const __attribute__((address_space(1))) void*)g,
        (__attribute__((address_space(3))) void*)l, 16, 0, 0);
}

// f32 -> f16 bulk convert (4 elements/thread)
__global__ void __launch_bounds__(256)
f2h_kernel(const float* __restrict__ src, half_t* __restrict__ dst, int n4)
{
    const int i = blockIdx.x * 256 + threadIdx.x;
    if (i < n4) {
        const float4 v = ((const float4*)src)[i];
        half_t o[4] = { (half_t)v.x, (half_t)v.y, (half_t)v.z, (half_t)v.w };
        ((uint2*)dst)[i] = *(const uint2*)o;
    }
}

// C = A(MxK,f16) @ W(NxK,f16)^T, fp32 acc; state tensors are fp32.
// MODE 0: out32 = C + bias[col]                                   (embed / head)
// MODE 3: hh1 = 0.5*tanh(bias+inp); out32 = 0.5*hh1 + 0.5*tanh(C+bias+inp);
//         out16 = f16(out32)                                      (2nd inner GEMM;
//          hh1 recomputed, so the first inner iteration needs no GEMM at all)
// MODE 1: hn = 0.5*hhold + 0.5*tanh(C+bias+inp); out32 = hn; out16 = f16(hn)
// MODE 2: hn = 0.5*hhold + 0.5*tanh(C+bias+inp); out32 = 0.5*aux + 0.5*hn
//         (last inner + outer mix; aux==out32==h, in-place)
template <int MODE>
__global__ void __launch_bounds__(256, 2)
gemm_bt(const half_t* __restrict__ A,
        const half_t* __restrict__ W,
        const float* __restrict__ bias,
        const float* __restrict__ inp,
        const float* hhold,           // no restrict (aliases out32 in MODE 1)
        const float* aux,             // no restrict (aliases out32 in MODE 2)
        float* out32,
        half_t* __restrict__ out16,
        int M, int N, int K)
{
    const int n = blockIdx.z;
    A    += (size_t)n * M * K;
    W    += (size_t)n * N * K;
    bias += (size_t)n * N;
    if (MODE != 0) {
        const size_t so = (size_t)n * M * N;
        inp += so; out32 += so;
        if (MODE == 1 || MODE == 2) hhold += so;
        if (MODE == 2) aux += so;
        if (MODE != 2) out16 += so;
    }

    const int tileM = blockIdx.y * 128;
    const int tileN = blockIdx.x * 128;

    __shared__ __attribute__((aligned(16))) half_t lA[128 * 32];   // 8 KB
    __shared__ __attribute__((aligned(16))) half_t lB[128 * 32];   // 8 KB

    const int tid  = threadIdx.x;
    const int wave = tid >> 6;
    const int lane = tid & 63;
    const int q    = lane >> 4;      // quad 0..3
    const int r16  = lane & 15;
    const int wm   = wave >> 1;      // wave's 64x64 subtile
    const int wn   = wave & 1;

    // staging geometry: lane i's 16B lands at lds_base + i*16
    const int srow = lane >> 2;          // row within 16-row chunk
    const int scol = (lane & 3) * 8;     // k offset (elements)

    frag_cd acc[4][4];
#pragma unroll
    for (int mt = 0; mt < 4; ++mt)
#pragma unroll
        for (int nt = 0; nt < 4; ++nt)
            acc[mt][nt] = (frag_cd){0.f, 0.f, 0.f, 0.f};

    for (int k0 = 0; k0 < K; k0 += 32) {
        __syncthreads();   // previous compute done before overwriting LDS
#pragma unroll
        for (int i = 0; i < 2; ++i) {
            const int rbase = wave * 32 + i * 16;
            gload16(A + (size_t)(tileM + rbase + srow) * K + k0 + scol, (void*)&lA[rbase * 32]);
            gload16(W + (size_t)(tileN + rbase + srow) * K + k0 + scol, (void*)&lB[rbase * 32]);
        }
        __syncthreads();   // drains vmcnt: LDS tiles visible

        frag_ab av[4], bv[4];
#pragma unroll
        for (int mt = 0; mt < 4; ++mt)
            av[mt] = *(const frag_ab*)&lA[(wm * 64 + mt * 16 + r16) * 32 + q * 8];
#pragma unroll
        for (int nt = 0; nt < 4; ++nt)
            bv[nt] = *(const frag_ab*)&lB[(wn * 64 + nt * 16 + r16) * 32 + q * 8];
#pragma unroll
        for (int mt = 0; mt < 4; ++mt)
#pragma unroll
            for (int nt = 0; nt < 4; ++nt)
                acc[mt][nt] = __builtin_amdgcn_mfma_f32_16x16x32_f16(av[mt], bv[nt], acc[mt][nt], 0, 0, 0);
    }

    // epilogue; C/D layout: col = lane&15, row = quad*4 + reg
#pragma unroll
    for (int mt = 0; mt < 4; ++mt) {
#pragma unroll
        for (int nt = 0; nt < 4; ++nt) {
#pragma unroll
            for (int r = 0; r < 4; ++r) {
                const int row = tileM + wm * 64 + mt * 16 + q * 4 + r;
                const int col = tileN + wn * 64 + nt * 16 + r16;
                const size_t oidx = (size_t)row * N + col;
                const float v = acc[mt][nt][r];
                if (MODE == 0) {
                    out32[oidx] = v + bias[col];
                } else {
                    const float iv  = inp[oidx];
                    const float bs  = bias[col];
                    const float t   = tanhf(v + bs + iv);
                    float ho;
                    if (MODE == 3) ho = 0.5f * tanhf(bs + iv);   // recomputed hh1
                    else           ho = hhold[oidx];
                    const float hn = 0.5f * ho + 0.5f * t;
                    if (MODE == 2) {
                        out32[oidx] = 0.5f * aux[oidx] + 0.5f * hn;
                    } else {
                        out32[oidx] = hn;
                        out16[oidx] = (half_t)hn;
                    }
                }
            }
        }
    }
}

// Per outer step: inp[n] = h[n] + (n==0 ? x_emb : h[n-1])  (all fp32)
// hhh = f16(0.5*tanh(bb[n] + inp))   (first inner iteration, GEMM-free)
__global__ void __launch_bounds__(256)
pre_outer_kernel(const float* __restrict__ h,
                 const float* __restrict__ x_emb,
                 const float* __restrict__ bb,   // NB x H (fp32)
                 float* __restrict__ inp,
                 half_t* __restrict__ hhh)
{
    const size_t idx = ((size_t)blockIdx.x * 256 + threadIdx.x) * 4;
    const int    n   = (int)(idx / ((size_t)B_DIM * H_DIM));
    const size_t off = idx - (size_t)n * B_DIM * H_DIM;
    const int    col = (int)(off & (H_DIM - 1));

    const float4 ha = *(const float4*)&h[idx];
    const float4 pa = (n == 0) ? *(const float4*)&x_emb[off]
                               : *(const float4*)&h[idx - (size_t)B_DIM * H_DIM];
    const float4 ba = *(const float4*)&bb[(size_t)n * H_DIM + col];

    const float* hp = (const float*)&ha;
    const float* pp = (const float*)&pa;
    const float* bp = (const float*)&ba;
    float  iv[4];
    half_t hv[4];
#pragma unroll
    for (int j = 0; j < 4; ++j) {
        const float in_v = hp[j] + pp[j];
        iv[j] = in_v;
        hv[j] = (half_t)(0.5f * tanhf(bp[j] + in_v));
    }
    *(float4*)&inp[idx] = *(const float4*)iv;
    *(uint2*)&hhh[idx]  = *(const uint2*)hv;
}

static inline void conv(const float* src, half_t* dst, int n, hipStream_t s) {
    const int n4 = n / 4;
    f2h_kernel<<<(n4 + 255) / 256, 256, 0, s>>>(src, dst, n4);
}

extern "C" void kernel_launch(void* const* d_in, const int* in_sizes, int n_in,
                              void* d_out, int out_size, void* d_ws, size_t ws_size,
                              hipStream_t stream)
{
    // Inputs/outputs are float32 (reference dtype).
    const float* x     = (const float*)d_in[0];   // B x DIN
    const float* embW  = (const float*)d_in[1];   // H x DIN
    const float* embB  = (const float*)d_in[2];   // H
    const float* blkW  = (const float*)d_in[3];   // NB x H x H
    const float* blkB  = (const float*)d_in[4];   // NB x H
    const float* headW = (const float*)d_in[5];   // DOUT x H
    const float* headB = (const float*)d_in[6];   // DOUT
    float* out = (float*)d_out;                   // B x DOUT

    char* ws = (char*)d_ws;
    size_t off = 0;
    auto alloc = [&](size_t bytes) {
        void* p = ws + off;
        off += (bytes + 255) & ~(size_t)255;
        return p;
    };
    const size_t NE = (size_t)NB * B_DIM * H_DIM;   // 10.5M elements

    // fp32 state
    float* h32    = (float*)alloc(NE * 4);          // 40 MB
    float* inp32  = (float*)alloc(NE * 4);          // 40 MB
    float* hh32   = (float*)alloc(NE * 4);          // 40 MB (in-place updated)
    float* xemb32 = (float*)alloc((size_t)B_DIM * H_DIM * 4);  // 4 MB
    // fp16 shadows / weights
    half_t* hhh0   = (half_t*)alloc(NE * 2);        // 20 MB
    half_t* hhh1   = (half_t*)alloc(NE * 2);        // 20 MB
    half_t* wx     = (half_t*)alloc((size_t)B_DIM * DIN * 2);
    half_t* wembW  = (half_t*)alloc((size_t)H_DIM * DIN * 2);
    half_t* wblkW  = (half_t*)alloc((size_t)NB * H_DIM * H_DIM * 2); // 20 MB
    half_t* wheadW = (half_t*)alloc((size_t)DOUT * H_DIM * 2);
    half_t* h9h    = (half_t*)alloc((size_t)B_DIM * H_DIM * 2);      // 2 MB
    (void)ws_size;  // total ~190 MB

    // one-time f32 -> f16 conversion of GEMM operands
    conv(x,     wx,     B_DIM * DIN,        stream);
    conv(embW,  wembW,  H_DIM * DIN,        stream);
    conv(blkW,  wblkW,  NB * H_DIM * H_DIM, stream);
    conv(headW, wheadW, DOUT * H_DIM,       stream);

    hipMemsetAsync(h32, 0, NE * 4, stream);   // h0 = zeros

    const dim3 blk(256);

    // x_emb = x @ embed_W^T + embed_b   (fp32 out)
    gemm_bt<0><<<dim3(H_DIM / 128, B_DIM / 128, 1), blk, 0, stream>>>(
        wx, wembW, embB, nullptr, nullptr, nullptr, xemb32, nullptr,
        B_DIM, H_DIM, DIN);

    const dim3 ggrid(H_DIM / 128, B_DIM / 128, NB);
    const int pre_blocks = (int)(NE / (4 * 256));
    for (int s = 0; s < STEPS; ++s) {
        // iteration 1 (GEMM-free, hh=0) + inp build
        pre_outer_kernel<<<pre_blocks, blk, 0, stream>>>(h32, xemb32, blkB, inp32, hhh0);
        // iteration 2: hhold=hh1 recomputed in epilogue
        gemm_bt<3><<<ggrid, blk, 0, stream>>>(hhh0, wblkW, blkB, inp32, nullptr, nullptr,
                                              hh32, hhh1, B_DIM, H_DIM, H_DIM);
        // iterations 3,4
        gemm_bt<1><<<ggrid, blk, 0, stream>>>(hhh1, wblkW, blkB, inp32, hh32, nullptr,
                                              hh32, hhh0, B_DIM, H_DIM, H_DIM);
        gemm_bt<1><<<ggrid, blk, 0, stream>>>(hhh0, wblkW, blkB, inp32, hh32, nullptr,
                                              hh32, hhh1, B_DIM, H_DIM, H_DIM);
        // iteration 5 fused with outer mix: h = 0.5h + 0.5*(0.5*hh + 0.5*tanh(...))
        gemm_bt<2><<<ggrid, blk, 0, stream>>>(hhh1, wblkW, blkB, inp32, hh32, h32,
                                              h32, nullptr, B_DIM, H_DIM, H_DIM);
    }

    // head input: f16(h[NB-1])
    conv(h32 + (size_t)(NB - 1) * B_DIM * H_DIM, h9h, B_DIM * H_DIM, stream);
    // out = h[NB-1] @ head_W^T + head_b   (fp32 out)
    gemm_bt<0><<<dim3(DOUT / 128, B_DIM / 128, 1), blk, 0, stream>>>(
        h9h, wheadW, headB, nullptr, nullptr, nullptr, out, nullptr,
        B_DIM, DOUT, H_DIM);
}

// Round 5
// 7470.996 us; speedup vs baseline: 1.3105x; 1.3105x over previous
//
#include <hip/hip_runtime.h>
#include <cstdint>
#include <cstddef>

// Problem constants (steps=30 is a fixed scalar input — hardcoded for a fixed
// graph-captured launch sequence).
#define B_DIM  1024
#define DIN    512
#define H_DIM  1024
#define DOUT   512
#define NB     10
#define STEPS  30

typedef _Float16 half_t;
typedef __attribute__((ext_vector_type(8))) _Float16 frag_ab;  // 8 fp16 in 4 VGPRs
typedef __attribute__((ext_vector_type(4))) float    frag_cd;  // 4 fp32 acc

// async global->LDS, 16B per lane; LDS dest is wave-uniform base + lane*16
__device__ __forceinline__ void gload16(const void* g, void* l) {
    __builtin_amdgcn_global_load_lds(
        (const __attribute__((address_space(1))) void*)g,
        (__attribute__((address_space(3))) void*)l, 16, 0, 0);
}

// f32 -> f16 bulk convert (4 elements/thread)
__global__ void __launch_bounds__(256)
f2h_kernel(const float* __restrict__ src, half_t* __restrict__ dst, int n4)
{
    const int i = blockIdx.x * 256 + threadIdx.x;
    if (i < n4) {
        const float4 v = ((const float4*)src)[i];
        half_t o[4] = { (half_t)v.x, (half_t)v.y, (half_t)v.z, (half_t)v.w };
        ((uint2*)dst)[i] = *(const uint2*)o;
    }
}

// C = A(MxK,f16) @ W(NxK,f16)^T, fp32 acc. Tile 128M x 64N, 256 thr, 4 waves.
// hh state lives ONLY in fp16 (A/out16); h state is fp32.
// MODE 0: out32 = C + bias[col]                                  (embed / head)
// MODE 3: hh1 = 0.5*tanh(bias+inp); out16 = 0.5*hh1 + 0.5*tanh(C+bias+inp)
//         (2nd inner GEMM; hh1 recomputed so iter 1 needs no GEMM)
// MODE 1: out16 = 0.5*A[row,col] + 0.5*tanh(C+bias+inp)          (iters 3,4; K==N)
// MODE 2: hn = 0.5*A[row,col] + 0.5*tanh(C+bias+inp);
//         out32 = 0.5*aux + 0.5*hn                               (iter 5 + outer mix;
//                                                                 aux==out32==h, in-place)
template <int MODE>
__global__ void __launch_bounds__(256, 4)
gemm_bt(const half_t* __restrict__ A,
        const half_t* __restrict__ W,
        const float* __restrict__ bias,
        const float* __restrict__ inp,
        const float* aux,             // no restrict (aliases out32 in MODE 2)
        float* out32,
        half_t* __restrict__ out16,
        int M, int N, int K)
{
    const int n = blockIdx.z;
    A    += (size_t)n * M * K;
    W    += (size_t)n * N * K;
    bias += (size_t)n * N;
    if (MODE != 0) {
        const size_t so = (size_t)n * M * N;
        inp += so;
        if (MODE == 2) { out32 += so; aux += so; }
        else           { out16 += so; }
    }

    const int tileM = blockIdx.y * 128;
    const int tileN = blockIdx.x * 64;

    __shared__ __attribute__((aligned(16))) half_t lA[128 * 32];   // 8 KB
    __shared__ __attribute__((aligned(16))) half_t lB[ 64 * 32];   // 4 KB

    const int tid  = threadIdx.x;
    const int wave = tid >> 6;
    const int lane = tid & 63;
    const int q    = lane >> 4;      // quad 0..3
    const int r16  = lane & 15;
    const int wm   = wave >> 1;      // 0..1: 64-row half
    const int wn   = wave & 1;       // 0..1: 32-col half

    // staging geometry: lane i's 16B lands at lds_base + i*16
    const int srow = lane >> 2;          // row within 16-row chunk
    const int scol = (lane & 3) * 8;     // k offset (elements)

    frag_cd acc[4][2];
#pragma unroll
    for (int mt = 0; mt < 4; ++mt)
#pragma unroll
        for (int nt = 0; nt < 2; ++nt)
            acc[mt][nt] = (frag_cd){0.f, 0.f, 0.f, 0.f};

    for (int k0 = 0; k0 < K; k0 += 32) {
        __syncthreads();   // previous compute done before overwriting LDS
#pragma unroll
        for (int i = 0; i < 2; ++i) {
            const int rbase = wave * 32 + i * 16;
            gload16(A + (size_t)(tileM + rbase + srow) * K + k0 + scol, (void*)&lA[rbase * 32]);
        }
        gload16(W + (size_t)(tileN + wave * 16 + srow) * K + k0 + scol, (void*)&lB[wave * 16 * 32]);
        __syncthreads();   // drains vmcnt: LDS tiles visible

        frag_ab av[4], bv[2];
#pragma unroll
        for (int mt = 0; mt < 4; ++mt)
            av[mt] = *(const frag_ab*)&lA[(wm * 64 + mt * 16 + r16) * 32 + q * 8];
#pragma unroll
        for (int nt = 0; nt < 2; ++nt)
            bv[nt] = *(const frag_ab*)&lB[(wn * 32 + nt * 16 + r16) * 32 + q * 8];
#pragma unroll
        for (int mt = 0; mt < 4; ++mt)
#pragma unroll
            for (int nt = 0; nt < 2; ++nt)
                acc[mt][nt] = __builtin_amdgcn_mfma_f32_16x16x32_f16(av[mt], bv[nt], acc[mt][nt], 0, 0, 0);
    }

    // epilogue; C/D layout: col = lane&15, row = quad*4 + reg
#pragma unroll
    for (int mt = 0; mt < 4; ++mt) {
#pragma unroll
        for (int nt = 0; nt < 2; ++nt) {
#pragma unroll
            for (int r = 0; r < 4; ++r) {
                const int row = tileM + wm * 64 + mt * 16 + q * 4 + r;
                const int col = tileN + wn * 32 + nt * 16 + r16;
                const size_t oidx = (size_t)row * N + col;
                const float v = acc[mt][nt][r];
                if (MODE == 0) {
                    out32[oidx] = v + bias[col];
                } else {
                    const float iv = inp[oidx];
                    const float bs = bias[col];
                    const float t  = tanhf(v + bs + iv);
                    const float ho = (MODE == 3) ? 0.5f * tanhf(bs + iv)
                                                 : (float)A[(size_t)row * K + col];
                    const float hn = 0.5f * ho + 0.5f * t;
                    if (MODE == 2) out32[oidx] = 0.5f * aux[oidx] + 0.5f * hn;
                    else           out16[oidx] = (half_t)hn;
                }
            }
        }
    }
}

// Per outer step: inp[n] = h[n] + (n==0 ? x_emb : h[n-1])  (fp32)
// hhh = f16(0.5*tanh(bb[n] + inp))   (first inner iteration, GEMM-free)
__global__ void __launch_bounds__(256)
pre_outer_kernel(const float* __restrict__ h,
                 const float* __restrict__ x_emb,
                 const float* __restrict__ bb,   // NB x H (fp32)
                 float* __restrict__ inp,
                 half_t* __restrict__ hhh)
{
    const size_t idx = ((size_t)blockIdx.x * 256 + threadIdx.x) * 4;
    const int    n   = (int)(idx / ((size_t)B_DIM * H_DIM));
    const size_t off = idx - (size_t)n * B_DIM * H_DIM;
    const int    col = (int)(off & (H_DIM - 1));

    const float4 ha = *(const float4*)&h[idx];
    const float4 pa = (n == 0) ? *(const float4*)&x_emb[off]
                               : *(const float4*)&h[idx - (size_t)B_DIM * H_DIM];
    const float4 ba = *(const float4*)&bb[(size_t)n * H_DIM + col];

    const float* hp = (const float*)&ha;
    const float* pp = (const float*)&pa;
    const float* bp = (const float*)&ba;
    float  iv[4];
    half_t hv[4];
#pragma unroll
    for (int j = 0; j < 4; ++j) {
        const float in_v = hp[j] + pp[j];
        iv[j] = in_v;
        hv[j] = (half_t)(0.5f * tanhf(bp[j] + in_v));
    }
    *(float4*)&inp[idx] = *(const float4*)iv;
    *(uint2*)&hhh[idx]  = *(const uint2*)hv;
}

static inline void conv(const float* src, half_t* dst, int n, hipStream_t s) {
    const int n4 = n / 4;
    f2h_kernel<<<(n4 + 255) / 256, 256, 0, s>>>(src, dst, n4);
}

extern "C" void kernel_launch(void* const* d_in, const int* in_sizes, int n_in,
                              void* d_out, int out_size, void* d_ws, size_t ws_size,
                              hipStream_t stream)
{
    // Inputs/outputs are float32 (reference dtype).
    const float* x     = (const float*)d_in[0];   // B x DIN
    const float* embW  = (const float*)d_in[1];   // H x DIN
    const float* embB  = (const float*)d_in[2];   // H
    const float* blkW  = (const float*)d_in[3];   // NB x H x H
    const float* blkB  = (const float*)d_in[4];   // NB x H
    const float* headW = (const float*)d_in[5];   // DOUT x H
    const float* headB = (const float*)d_in[6];   // DOUT
    float* out = (float*)d_out;                   // B x DOUT

    char* ws = (char*)d_ws;
    size_t off = 0;
    auto alloc = [&](size_t bytes) {
        void* p = ws + off;
        off += (bytes + 255) & ~(size_t)255;
        return p;
    };
    const size_t NE = (size_t)NB * B_DIM * H_DIM;   // 10.5M elements

    // fp32 state
    float* h32    = (float*)alloc(NE * 4);          // 40 MB
    float* inp32  = (float*)alloc(NE * 4);          // 40 MB
    float* xemb32 = (float*)alloc((size_t)B_DIM * H_DIM * 4);  // 4 MB
    // fp16 state / weights
    half_t* hhh0   = (half_t*)alloc(NE * 2);        // 20 MB
    half_t* hhh1   = (half_t*)alloc(NE * 2);        // 20 MB
    half_t* wx     = (half_t*)alloc((size_t)B_DIM * DIN * 2);
    half_t* wembW  = (half_t*)alloc((size_t)H_DIM * DIN * 2);
    half_t* wblkW  = (half_t*)alloc((size_t)NB * H_DIM * H_DIM * 2); // 20 MB
    half_t* wheadW = (half_t*)alloc((size_t)DOUT * H_DIM * 2);
    half_t* h9h    = (half_t*)alloc((size_t)B_DIM * H_DIM * 2);      // 2 MB
    (void)ws_size;  // total ~150 MB

    // one-time f32 -> f16 conversion of GEMM operands
    conv(x,     wx,     B_DIM * DIN,        stream);
    conv(embW,  wembW,  H_DIM * DIN,        stream);
    conv(blkW,  wblkW,  NB * H_DIM * H_DIM, stream);
    conv(headW, wheadW, DOUT * H_DIM,       stream);

    hipMemsetAsync(h32, 0, NE * 4, stream);   // h0 = zeros

    const dim3 blk(256);

    // x_emb = x @ embed_W^T + embed_b   (fp32 out)
    gemm_bt<0><<<dim3(H_DIM / 64, B_DIM / 128, 1), blk, 0, stream>>>(
        wx, wembW, embB, nullptr, nullptr, xemb32, nullptr, B_DIM, H_DIM, DIN);

    const dim3 ggrid(H_DIM / 64, B_DIM / 128, NB);   // 16 x 8 x 10 = 1280 blocks
    const int pre_blocks = (int)(NE / (4 * 256));
    for (int s = 0; s < STEPS; ++s) {
        // iteration 1 (GEMM-free, hh=0) + inp build
        pre_outer_kernel<<<pre_blocks, blk, 0, stream>>>(h32, xemb32, blkB, inp32, hhh0);
        // iteration 2: hh1 recomputed in epilogue
        gemm_bt<3><<<ggrid, blk, 0, stream>>>(hhh0, wblkW, blkB, inp32, nullptr,
                                              nullptr, hhh1, B_DIM, H_DIM, H_DIM);
        // iterations 3,4 (hhold re-read from the fp16 A buffer)
        gemm_bt<1><<<ggrid, blk, 0, stream>>>(hhh1, wblkW, blkB, inp32, nullptr,
                                              nullptr, hhh0, B_DIM, H_DIM, H_DIM);
        gemm_bt<1><<<ggrid, blk, 0, stream>>>(hhh0, wblkW, blkB, inp32, nullptr,
                                              nullptr, hhh1, B_DIM, H_DIM, H_DIM);
        // iteration 5 fused with outer mix: h = 0.5h + 0.5*(0.5*hh + 0.5*tanh(...))
        gemm_bt<2><<<ggrid, blk, 0, stream>>>(hhh1, wblkW, blkB, inp32, h32,
                                              h32, nullptr, B_DIM, H_DIM, H_DIM);
    }

    // head input: f16(h[NB-1])
    conv(h32 + (size_t)(NB - 1) * B_DIM * H_DIM, h9h, B_DIM * H_DIM, stream);
    // out = h[NB-1] @ head_W^T + head_b   (fp32 out)
    gemm_bt<0><<<dim3(DOUT / 64, B_DIM / 128, 1), blk, 0, stream>>>(
        h9h, wheadW, headB, nullptr, nullptr, out, nullptr, B_DIM, DOUT, H_DIM);
}